// Round 8
// baseline (222.925 us; speedup 1.0000x reference)
//
#include <hip/hip_runtime.h>
#include <stdint.h>

constexpr int K      = 49;           // 7x7 kernel flattened
constexpr int C      = 32;           // out channels
constexpr int TILE   = 64;           // windows per block
constexpr int TILE_F = TILE * K;     // 3136 floats = 12544 B
constexpr int BLK    = 128;          // 2 waves/block, 16 channels each

#define GPTR(p) ((const __attribute__((address_space(1))) uint32_t*)(p))
#define LPTR(p) ((__attribute__((address_space(3))) uint32_t*)(p))

// 2 waves share one 12.5 KB tile: 12 blocks/CU -> 24 waves/CU.
// Wave 0 computes channels 0-15, wave 1 channels 16-31 (wave-uniform weight
// base -> scalar s_loads). k split in two register halves keeps VGPR <= 64.
__global__ __launch_bounds__(BLK, 8) void conv2d_split2(
    const float* __restrict__ enc_x,
    const float* __restrict__ weight,   // [C*K]
    const float* __restrict__ bias,     // [C]
    float* __restrict__ out,            // [C * windows_nb]
    int windows_nb)
{
    __shared__ __align__(16) float xs[TILE_F];   // 12544 B

    const int t    = threadIdx.x;
    const int lane = t & 63;
    const int wid  = t >> 6;                     // 0 or 1
    const size_t b = blockIdx.x;
    const float* __restrict__ g = enc_x + b * (size_t)TILE_F;

    // Stage 12544 B: wave0 -> rounds 0-5 (6x 64lane x 16B), wave1 -> rounds
    // 6-11 + 256 B tail (7 ops). Fully coalesced, single temporal burst.
    if (wid == 0) {
#pragma unroll
        for (int r = 0; r < 6; ++r)
            __builtin_amdgcn_global_load_lds(GPTR(g + r * 256 + lane * 4),
                                             LPTR(xs + r * 256 + lane * 4), 16, 0, 0);
    } else {
#pragma unroll
        for (int r = 6; r < 12; ++r)
            __builtin_amdgcn_global_load_lds(GPTR(g + r * 256 + lane * 4),
                                             LPTR(xs + r * 256 + lane * 4), 16, 0, 0);
        __builtin_amdgcn_global_load_lds(GPTR(g + 3072 + lane),
                                         LPTR(xs + 3072 + lane), 4, 0, 0);
    }

    asm volatile("s_waitcnt vmcnt(0)" ::: "memory");
    __builtin_amdgcn_s_barrier();                // tile resident (couples only 2 waves)

    const int c0 = wid * 16;
    const float* __restrict__ wp = weight + c0 * K;   // uniform -> s_load

    float acc[16];
#pragma unroll
    for (int cc = 0; cc < 16; ++cc) acc[cc] = bias[c0 + cc];

    // ---- k half 1: 0..23 ----
    // ds pattern xs[lane*49+k]: stride 49 (odd) -> 2 lanes/bank -> free.
    float x[25];
#pragma unroll
    for (int k = 0; k < 24; ++k) x[k] = xs[lane * K + k];
#pragma unroll 2                                  // 2 indep FMA chains cover latency
    for (int cc = 0; cc < 16; ++cc) {
        const float* __restrict__ wc = wp + cc * K;   // 24 consecutive -> wide s_load
        float a = acc[cc];
#pragma unroll
        for (int k = 0; k < 24; ++k) a = fmaf(x[k], wc[k], a);
        acc[cc] = a;
    }

    // ---- k half 2: 24..48 ----
#pragma unroll
    for (int k = 0; k < 25; ++k) x[k] = xs[lane * K + 24 + k];
#pragma unroll 2
    for (int cc = 0; cc < 16; ++cc) {
        const float* __restrict__ wc = wp + cc * K + 24;
        float a = acc[cc];
#pragma unroll
        for (int k = 0; k < 25; ++k) a = fmaf(x[k], wc[k], a);
        acc[cc] = a;
    }

    // 16 stores from distinct regs, nothing redefined after -> no store waits;
    // wave retires while writes drain.
    const size_t w = b * TILE + lane;
#pragma unroll
    for (int cc = 0; cc < 16; ++cc)
        out[(size_t)(c0 + cc) * windows_nb + w] = acc[cc];
}

extern "C" void kernel_launch(void* const* d_in, const int* in_sizes, int n_in,
                              void* d_out, int out_size, void* d_ws, size_t ws_size,
                              hipStream_t stream) {
    const float* enc_x  = (const float*)d_in[0];
    const float* weight = (const float*)d_in[1];   // [C,7,7] flat
    const float* bias   = (const float*)d_in[2];   // [C]
    float* out = (float*)d_out;

    const int windows_nb = in_sizes[0] / K;        // 1048576 (divisible by 64)
    const int nblocks = windows_nb / TILE;         // 16384

    conv2d_split2<<<nblocks, BLK, 0, stream>>>(enc_x, weight, bias, out, windows_nb);
}

// Round 9
// 79.536 us; speedup vs baseline: 2.8028x; 2.8028x over previous
//
#include <hip/hip_runtime.h>
#include <stdint.h>

constexpr int K      = 49;           // 7x7 kernel flattened
constexpr int C      = 32;           // out channels
constexpr int TILE   = 64;           // windows per block
constexpr int TILE_F = TILE * K;     // 3136 floats = 12544 B
constexpr int BLK    = 128;          // 2 waves/block, 16 channels each

#define GPTR(p) ((const __attribute__((address_space(1))) uint32_t*)(p))
#define LPTR(p) ((__attribute__((address_space(3))) uint32_t*)(p))

// 2 waves share one 12.5 KB tile: 12 blocks/CU -> 24 waves/CU.
// CRITICAL: channel base c0 goes through readfirstlane so the compiler
// proves wave-uniformity -> weight/bias reads stay SCALAR (s_load_dwordx16).
// (R3/R5/R8 regression root-cause: t>>6-derived base -> per-lane vector
// loads of weights, 2x VALU + L1-latency-serialized FMA chains.)
__global__ __launch_bounds__(BLK, 8) void conv2d_split2u(
    const float* __restrict__ enc_x,
    const float* __restrict__ weight,   // [C*K]
    const float* __restrict__ bias,     // [C]
    float* __restrict__ out,            // [C * windows_nb]
    int windows_nb)
{
    __shared__ __align__(16) float xs[TILE_F];   // 12544 B

    const int t    = threadIdx.x;
    const int lane = t & 63;
    const int wid  = t >> 6;                     // 0 or 1 (divergent form, staging only)
    const size_t b = blockIdx.x;
    const float* __restrict__ g = enc_x + b * (size_t)TILE_F;

    // Stage 12544 B: wave0 -> rounds 0-5, wave1 -> rounds 6-11 + 256 B tail.
    // Fully coalesced float4, single temporal burst, no VGPR round-trip.
    if (wid == 0) {
#pragma unroll
        for (int r = 0; r < 6; ++r)
            __builtin_amdgcn_global_load_lds(GPTR(g + r * 256 + lane * 4),
                                             LPTR(xs + r * 256 + lane * 4), 16, 0, 0);
    } else {
#pragma unroll
        for (int r = 6; r < 12; ++r)
            __builtin_amdgcn_global_load_lds(GPTR(g + r * 256 + lane * 4),
                                             LPTR(xs + r * 256 + lane * 4), 16, 0, 0);
        __builtin_amdgcn_global_load_lds(GPTR(g + 3072 + lane),
                                         LPTR(xs + 3072 + lane), 4, 0, 0);
    }

    asm volatile("s_waitcnt vmcnt(0)" ::: "memory");
    __builtin_amdgcn_s_barrier();                // tile resident (couples only 2 waves)

    // Wave-uniform channel base in an SGPR.
    const int c0 = __builtin_amdgcn_readfirstlane(wid) * 16;
    const float* __restrict__ wp = weight + c0 * K;   // SGPR base -> s_load

    float acc[16];
#pragma unroll
    for (int cc = 0; cc < 16; ++cc) acc[cc] = bias[c0 + cc];   // scalar loads

    // ---- k half 1: 0..23 ----  (xs stride 49: odd -> 2 lanes/bank, free)
    float x[25];
#pragma unroll
    for (int k = 0; k < 24; ++k) x[k] = xs[lane * K + k];
#pragma unroll 2                                  // 2 indep FMA chains cover s_load latency
    for (int cc = 0; cc < 16; ++cc) {
        const float* __restrict__ wc = wp + cc * K;   // 24 consecutive -> wide s_load
        float a = acc[cc];
#pragma unroll
        for (int k = 0; k < 24; ++k) a = fmaf(x[k], wc[k], a);
        acc[cc] = a;
    }

    // ---- k half 2: 24..48 ----
#pragma unroll
    for (int k = 0; k < 25; ++k) x[k] = xs[lane * K + 24 + k];
#pragma unroll 2
    for (int cc = 0; cc < 16; ++cc) {
        const float* __restrict__ wc = wp + cc * K + 24;
        float a = acc[cc];
#pragma unroll
        for (int k = 0; k < 25; ++k) a = fmaf(x[k], wc[k], a);
        acc[cc] = a;
    }

    // 16 stores from distinct regs (SGPR-uniform plane base), nothing
    // redefined after -> no store-completion waits; wave retires into drain.
    const size_t w = b * TILE + lane;
#pragma unroll
    for (int cc = 0; cc < 16; ++cc)
        out[(size_t)(c0 + cc) * windows_nb + w] = acc[cc];
}

extern "C" void kernel_launch(void* const* d_in, const int* in_sizes, int n_in,
                              void* d_out, int out_size, void* d_ws, size_t ws_size,
                              hipStream_t stream) {
    const float* enc_x  = (const float*)d_in[0];
    const float* weight = (const float*)d_in[1];   // [C,7,7] flat
    const float* bias   = (const float*)d_in[2];   // [C]
    float* out = (float*)d_out;

    const int windows_nb = in_sizes[0] / K;        // 1048576 (divisible by 64)
    const int nblocks = windows_nb / TILE;         // 16384

    conv2d_split2u<<<nblocks, BLK, 0, stream>>>(enc_x, weight, bias, out, windows_nb);
}